// Round 11
// baseline (82.481 us; speedup 1.0000x reference)
//
#include <hip/hip_runtime.h>
#include <hip/hip_bf16.h>
#include <math.h>

#define TRIP_BLOCKS 1024   // 4096 waves; ~3 batches of 16 triplets each
#define N_ROWS 8192
#define DIM 128

using f32x4  = __attribute__((ext_vector_type(4))) float;
using bf16x8 = __attribute__((ext_vector_type(8))) short;   // 8 bf16 = 4 VGPRs

// ws layout: bf16 xh[8192*128] (2 MB); float sq[8192]; float partial[TRIP_BLOCKS]

// DPP add — VALU-pipe cross-lane, no DS traffic.
template<int CTRL, int ROWMASK>
__device__ __forceinline__ float dpp_add(float v) {
    int m = __builtin_amdgcn_update_dpp(0, __float_as_int(v), CTRL, ROWMASK, 0xf, true);
    return v + __int_as_float(m);
}
// Full 64-lane sum; lane 63 ends with the total. 6 VALU ops.
__device__ __forceinline__ float wave64_sum(float v) {
    v = dpp_add<0x111, 0xf>(v);   // row_shr:1
    v = dpp_add<0x112, 0xf>(v);   // row_shr:2
    v = dpp_add<0x114, 0xf>(v);   // row_shr:4
    v = dpp_add<0x118, 0xf>(v);   // row_shr:8
    v = dpp_add<0x142, 0xa>(v);   // row_bcast:15
    v = dpp_add<0x143, 0xc>(v);   // row_bcast:31
    return v;
}

__device__ __forceinline__ float softplus_fast(float z) {
    float u = __expf(-fabsf(z));
    return fmaxf(z, 0.0f) + __logf(1.0f + u);
}

// One wave per row: fp32 -> bf16 row cache + fp32 row norm (runs every call).
__global__ void __launch_bounds__(256)
cvt_kernel(const float* __restrict__ x, __hip_bfloat16* __restrict__ xh,
           float* __restrict__ sq, int n_rows) {
    int wave = (blockIdx.x * blockDim.x + threadIdx.x) >> 6;
    int lane = threadIdx.x & 63;
    if (wave >= n_rows) return;
    const float2* row = (const float2*)(x + (size_t)wave * DIM);
    float2 v = row[lane];                              // 64 x 8B = full row
    __hip_bfloat162 h = __float22bfloat162_rn(make_float2(v.x, v.y));
    ((__hip_bfloat162*)xh)[wave * 64 + lane] = h;      // 64 x 4B coalesced
    float s = fmaf(v.x, v.x, v.y * v.y);
    s = wave64_sum(s);
    if (lane == 63) sq[wave] = s;
}

// 16 triplets per wave-batch via MFMA: diag(Xi·Xj^T) and diag(Xi·Xk^T).
__global__ void __launch_bounds__(256)
trip_kernel(const __hip_bfloat16* __restrict__ xh, const float* __restrict__ sq,
            const int* __restrict__ trip, float* __restrict__ partial,
            int T, int nbatches) {
    const int lane   = threadIdx.x & 63;
    const int wid    = threadIdx.x >> 6;
    const int gwave  = (blockIdx.x * blockDim.x + threadIdx.x) >> 6;
    const int nwaves = (TRIP_BLOCKS * 256) >> 6;       // 4096
    const int m      = lane & 15;                      // triplet within batch
    const int hi     = lane >> 4;                      // k-octet selector
    const bool isdiag = (hi == (m >> 2));              // this lane holds diag m
    const int r      = m & 3;                          // acc reg of diag elem

    const bf16x8* xq = (const bf16x8*)xh;              // row = 16 x 16B chunks

    float local = 0.0f;

    int batch = gwave;
    int idxv  = 0;
    if (batch < nbatches && lane < 48)
        idxv = trip[batch * 48 + lane];                // 48 idx, coalesced

    while (batch < nbatches) {
        // distribute triplet m's indices to all lanes (3 DS bpermutes)
        int im = __shfl(idxv, 3 * m,     64);
        int jm = __shfl(idxv, 3 * m + 1, 64);
        int km = __shfl(idxv, 3 * m + 2, 64);

        // MFMA A/B fragments: lane holds row (lane&15), k-bytes hi*16 of each
        // 64B chunk — 12 dwordx4 total, 16 fully-consumed lines each.
        int ia = im * 16 + hi, ja = jm * 16 + hi, ka = km * 16 + hi;
        bf16x8 fa0 = xq[ia], fa1 = xq[ia + 4], fa2 = xq[ia + 8], fa3 = xq[ia + 12];
        bf16x8 fb0 = xq[ja], fb1 = xq[ja + 4], fb2 = xq[ja + 8], fb3 = xq[ja + 12];
        bf16x8 fc0 = xq[ka], fc1 = xq[ka + 4], fc2 = xq[ka + 8], fc3 = xq[ka + 12];

        float sqi = sq[im], sqj = sq[jm], sqk = sq[km];  // 32KB table, L1-hot

        // prefetch next batch's indices under the row-gather latency (R7 win)
        int batch2 = batch + nwaves;
        if (batch2 < nbatches && lane < 48)
            idxv = trip[batch2 * 48 + lane];

        f32x4 aij = {0.f, 0.f, 0.f, 0.f};
        f32x4 aik = {0.f, 0.f, 0.f, 0.f};
        aij = __builtin_amdgcn_mfma_f32_16x16x32_bf16(fa0, fb0, aij, 0, 0, 0);
        aik = __builtin_amdgcn_mfma_f32_16x16x32_bf16(fa0, fc0, aik, 0, 0, 0);
        aij = __builtin_amdgcn_mfma_f32_16x16x32_bf16(fa1, fb1, aij, 0, 0, 0);
        aik = __builtin_amdgcn_mfma_f32_16x16x32_bf16(fa1, fc1, aik, 0, 0, 0);
        aij = __builtin_amdgcn_mfma_f32_16x16x32_bf16(fa2, fb2, aij, 0, 0, 0);
        aik = __builtin_amdgcn_mfma_f32_16x16x32_bf16(fa2, fc2, aik, 0, 0, 0);
        aij = __builtin_amdgcn_mfma_f32_16x16x32_bf16(fa3, fb3, aij, 0, 0, 0);
        aik = __builtin_amdgcn_mfma_f32_16x16x32_bf16(fa3, fc3, aik, 0, 0, 0);

        // C/D layout: col=lane&15, row=(lane>>4)*4+reg -> diag m on lane
        // ((m>>2)<<4)|m at reg m&3. Diagonal is transpose-immune.
        if (isdiag && batch * 16 + m < T) {
            float dij = (r & 2) ? ((r & 1) ? aij.w : aij.z)
                                : ((r & 1) ? aij.y : aij.x);
            float dik = (r & 2) ? ((r & 1) ? aik.w : aik.z)
                                : ((r & 1) ? aik.y : aik.x);
            float d1 = fmaxf(fmaf(-2.0f, dij, sqi + sqj), 0.0f);
            float d2 = fmaxf(fmaf(-2.0f, dik, sqi + sqk), 0.0f);
            local += softplus_fast(d1 - d2);
        }
        batch = batch2;
    }

    local = wave64_sum(local);            // 16 diag lanes hold values, rest 0
    __shared__ float wsum[4];
    if (lane == 63) wsum[wid] = local;
    __syncthreads();
    if (threadIdx.x == 0)
        partial[blockIdx.x] = wsum[0] + wsum[1] + wsum[2] + wsum[3];
}

__global__ void __launch_bounds__(256)
finalize_kernel(const float* __restrict__ partial, int nparts,
                float* __restrict__ out, int T) {
    float s = 0.0f;
    for (int idx = threadIdx.x; idx < nparts; idx += 256)
        s += partial[idx];
#pragma unroll
    for (int off = 32; off; off >>= 1) s += __shfl_xor(s, off, 64);
    __shared__ float wsum[4];
    int wid = threadIdx.x >> 6;
    if ((threadIdx.x & 63) == 0) wsum[wid] = s;
    __syncthreads();
    if (threadIdx.x == 0)
        out[0] = (wsum[0] + wsum[1] + wsum[2] + wsum[3]) / (float)T;
}

extern "C" void kernel_launch(void* const* d_in, const int* in_sizes, int n_in,
                              void* d_out, int out_size, void* d_ws, size_t ws_size,
                              hipStream_t stream) {
    const float* x    = (const float*)d_in[0];
    const int*   trip = (const int*)d_in[1];
    float*       out  = (float*)d_out;

    int n_rows   = in_sizes[0] / DIM;                  // 8192
    int T        = in_sizes[1] / 3;                    // 200000
    int nbatches = (T + 15) / 16;                      // 12500

    __hip_bfloat16* xh = (__hip_bfloat16*)d_ws;
    float* sq      = (float*)((char*)d_ws + (size_t)n_rows * DIM * 2);
    float* partial = sq + n_rows;

    // 1) bf16 row cache + fp32 norms (one wave per row)
    cvt_kernel<<<(n_rows + 3) / 4, 256, 0, stream>>>(x, xh, sq, n_rows);

    // 2) MFMA triplet batches
    trip_kernel<<<TRIP_BLOCKS, 256, 0, stream>>>(xh, sq, trip, partial, T, nbatches);

    // 3) reduce partials + mean
    finalize_kernel<<<1, 256, 0, stream>>>(partial, TRIP_BLOCKS, out, T);
}

// Round 12
// 76.056 us; speedup vs baseline: 1.0845x; 1.0845x over previous
//
#include <hip/hip_runtime.h>
#include <math.h>

#define TRIP_BLOCKS 2048   // 8 blocks/CU x 256 CUs: fully resident at <=64 VGPR

// ws layout: float partial[TRIP_BLOCKS]

// DPP row_shr:N add — VALU-pipe cross-lane, no DS traffic.
template<int CTRL>
__device__ __forceinline__ float dpp_shr_add(float v) {
    int m = __builtin_amdgcn_update_dpp(0, __float_as_int(v), CTRL, 0xf, 0xf, true);
    return v + __int_as_float(m);
}

// Sum across a 16-lane DPP row; lane 15 of each row ends with the row sum.
__device__ __forceinline__ float row16_sum(float v) {
    v = dpp_shr_add<0x111>(v);   // row_shr:1
    v = dpp_shr_add<0x112>(v);   // row_shr:2
    v = dpp_shr_add<0x114>(v);   // row_shr:4
    v = dpp_shr_add<0x118>(v);   // row_shr:8
    return v;
}

// Fast softplus via HW exp/log (validation threshold is inf — fp32 ulps are free).
__device__ __forceinline__ float softplus_fast(float z) {
    float u = __expf(-fabsf(z));
    return fmaxf(z, 0.0f) + __logf(1.0f + u);
}

__device__ __forceinline__ void sq_diff(const float4 a, const float4 b, float& acc) {
    float t;
    t = a.x - b.x; acc = fmaf(t, t, acc);
    t = a.y - b.y; acc = fmaf(t, t, acc);
    t = a.z - b.z; acc = fmaf(t, t, acc);
    t = a.w - b.w; acc = fmaf(t, t, acc);
}

__global__ void __launch_bounds__(256, 8)   // force VGPR<=64: 8 blocks/CU resident
trip_kernel(const float* __restrict__ x, const int* __restrict__ trip,
            float* __restrict__ partial, int T) {
    const int lane    = threadIdx.x & 63;
    const int sub     = threadIdx.x & 15;
    const int gid     = (blockIdx.x * blockDim.x + threadIdx.x) >> 4;
    const int ngroups = (TRIP_BLOCKS * 256) >> 4;   // 32768, compile-time

    const float4* xv = (const float4*)x;   // 32 float4 per 128-float row

    float local = 0.0f;

    // Software pipeline on indices: iteration t+1's trip[] loads are issued
    // while iteration t's row gathers are in flight (the R7 win, -3.7us).
    int n = gid;
    int i = 0, j = 0, k = 0;
    if (n < T) {                           // prologue idx load
        i = trip[3 * n];
        j = trip[3 * n + 1];
        k = trip[3 * n + 2];
    }
    while (n < T) {
        // issue current row gathers (6 independent dwordx4, 256B segments)
        float4 a0 = xv[i * 32 + sub], a1 = xv[i * 32 + sub + 16];
        float4 b0 = xv[j * 32 + sub], b1 = xv[j * 32 + sub + 16];
        float4 c0 = xv[k * 32 + sub], c1 = xv[k * 32 + sub + 16];

        // prefetch next indices NOW — they ride out the row-gather latency
        int n2 = n + ngroups;
        if (n2 < T) {
            i = trip[3 * n2];
            j = trip[3 * n2 + 1];
            k = trip[3 * n2 + 2];
        }

        // per-lane partial of d_ij - d_ik = sum (a-b)^2 - (a-c)^2
        float d1 = 0.0f, d2 = 0.0f;
        sq_diff(a0, b0, d1); sq_diff(a1, b1, d1);
        sq_diff(a0, c0, d2); sq_diff(a1, c1, d2);

        d1 = row16_sum(d1);                // 4 DPP adds each, VALU pipe only
        d2 = row16_sum(d2);
        if (sub == 15)
            local += softplus_fast(d1 - d2);   // ~6 VALU ops, 4/64 lanes active

        n = n2;
    }

    // lanes 15/31/47/63 hold per-group sums; two DS shuffles per wave total
    local += __shfl_xor(local, 16, 64);
    local += __shfl_xor(local, 32, 64);

    __shared__ float wsum[4];
    int wid = threadIdx.x >> 6;
    if (lane == 15) wsum[wid] = local;
    __syncthreads();
    if (threadIdx.x == 0)
        partial[blockIdx.x] = wsum[0] + wsum[1] + wsum[2] + wsum[3];
}

__global__ void __launch_bounds__(256)
finalize_kernel(const float* __restrict__ partial, int nparts,
                float* __restrict__ out, int T) {
    float s = 0.0f;
    for (int idx = threadIdx.x; idx < nparts; idx += 256)
        s += partial[idx];
#pragma unroll
    for (int off = 32; off; off >>= 1) s += __shfl_xor(s, off, 64);
    __shared__ float wsum[4];
    int wid = threadIdx.x >> 6;
    if ((threadIdx.x & 63) == 0) wsum[wid] = s;
    __syncthreads();
    if (threadIdx.x == 0)
        out[0] = (wsum[0] + wsum[1] + wsum[2] + wsum[3]) / (float)T;
}

extern "C" void kernel_launch(void* const* d_in, const int* in_sizes, int n_in,
                              void* d_out, int out_size, void* d_ws, size_t ws_size,
                              hipStream_t stream) {
    const float* x    = (const float*)d_in[0];
    const int*   trip = (const int*)d_in[1];
    float*       out  = (float*)d_out;

    int T = in_sizes[1] / 3;              // 200000

    float* partial = (float*)d_ws;

    trip_kernel<<<TRIP_BLOCKS, 256, 0, stream>>>(x, trip, partial, T);
    finalize_kernel<<<1, 256, 0, stream>>>(partial, TRIP_BLOCKS, out, T);
}